// Round 8
// baseline (494.716 us; speedup 1.0000x reference)
//
#include <hip/hip_runtime.h>
#include <hip/hip_bf16.h>
#include <stdint.h>

// Problem constants
#define BB 4
#define SS 2048
#define DD 1024
#define HH 16
#define DHH 128   // per-head dim after concat (2*64)

typedef __bf16 bf16x8 __attribute__((ext_vector_type(8)));
typedef __bf16 bf16x4 __attribute__((ext_vector_type(4)));
typedef float  f32x4  __attribute__((ext_vector_type(4)));
typedef short  short4v __attribute__((ext_vector_type(4)));

// (1/sqrt(64)) * log2(e), folded into Q at GEMM epilogue time
#define SL2E 0.180336880111186f

#if __has_builtin(__builtin_amdgcn_exp2f)
#define EXP2(x) __builtin_amdgcn_exp2f(x)
#else
#define EXP2(x) exp2f(x)
#endif

// async global->LDS, 16B per lane; LDS dest is wave-uniform base + lane*16,
// global src is per-lane (gather allowed)
#define GLOAD_LDS16(gp, lp) \
  __builtin_amdgcn_global_load_lds((const __attribute__((address_space(1))) unsigned int*)(gp), \
                                   (__attribute__((address_space(3))) unsigned int*)(lp), 16, 0, 0)

// 16x16x16 bf16 MFMA (k=16): B-operand k = quad*4+j == S^T C-layout rows.
static __device__ inline f32x4 mfma16(short4v a, short4v b, f32x4 c) {
#if __has_builtin(__builtin_amdgcn_mfma_f32_16x16x16bf16_1k)
    return __builtin_amdgcn_mfma_f32_16x16x16bf16_1k(a, b, c, 0, 0, 0);
#else
    asm volatile("v_mfma_f32_16x16x16_bf16 %0, %1, %2, %0" : "+v"(c) : "v"(a), "v"(b));
    return c;
#endif
}

static __device__ inline short4v pack4(f32x4 v) {
    bf16x4 t;
    t[0] = (__bf16)v[0]; t[1] = (__bf16)v[1]; t[2] = (__bf16)v[2]; t[3] = (__bf16)v[3];
    return __builtin_bit_cast(short4v, t);
}

// ---------------------------------------------------------------------------
// Fused cast of x and c -> bf16 (dest xb and cb are contiguous)
__global__ void cast2_kernel(const float* __restrict__ x, const float* __restrict__ c,
                             __bf16* __restrict__ out, int n) {
    int i = (blockIdx.x * blockDim.x + threadIdx.x) * 4;
    const float* src = (i < n) ? (x + i) : (c + (i - n));
    f32x4 v = *(const f32x4*)src;
    bf16x4 o;
    o[0] = (__bf16)v[0]; o[1] = (__bf16)v[1]; o[2] = (__bf16)v[2]; o[3] = (__bf16)v[3];
    *(bf16x4*)(out + i) = o;
}

// ---------------------------------------------------------------------------
// Transpose + cast: W[K][N] fp32 -> Wt[N][K] bf16 (used for W_proj)
__global__ void transpose_cast_kernel(const float* __restrict__ in, __bf16* __restrict__ out,
                                      int K, int N) {
    __shared__ float tile[32][33];
    int n0 = blockIdx.x * 32, k0 = blockIdx.y * 32;
    int tx = threadIdx.x, ty = threadIdx.y;   // 32 x 8
    #pragma unroll
    for (int i = 0; i < 32; i += 8)
        tile[ty + i][tx] = in[(size_t)(k0 + ty + i) * N + n0 + tx];
    __syncthreads();
    #pragma unroll
    for (int i = 0; i < 32; i += 8)
        out[(size_t)(n0 + ty + i) * K + k0 + tx] = (__bf16)tile[tx][ty + i];
}

// Fused transpose+cast of the six 1024x1024 QKV weights into contiguous dst
// Order: Wq_x, Wk_x, Wv_x, Wq_c, Wk_c, Wv_c  (Q,K adjacent per input for fusion)
__global__ void transpose6_kernel(const float* s0, const float* s1, const float* s2,
                                  const float* s3, const float* s4, const float* s5,
                                  __bf16* __restrict__ dst) {
    const float* srcs[6] = {s0, s1, s2, s3, s4, s5};
    const float* __restrict__ in = srcs[blockIdx.z];
    __bf16* __restrict__ out = dst + (size_t)blockIdx.z * 1024 * 1024;
    __shared__ float tile[32][33];
    int n0 = blockIdx.x * 32, k0 = blockIdx.y * 32;
    int tx = threadIdx.x, ty = threadIdx.y;   // 32 x 8
    #pragma unroll
    for (int i = 0; i < 32; i += 8)
        tile[ty + i][tx] = in[(size_t)(k0 + ty + i) * 1024 + n0 + tx];
    __syncthreads();
    #pragma unroll
    for (int i = 0; i < 32; i += 8)
        out[(size_t)(n0 + ty + i) * 1024 + k0 + tx] = (__bf16)tile[tx][ty + i];
}

// ---------------------------------------------------------------------------
// GEMM: C = A @ Bt^T (bf16, both contiguous in K), 128x128 tile, BK=32,
// global_load_lds staging, 4 waves, 4x4 16x16x32 subtiles.
// EPI 1: fp32 -> out[M][1024] + bias  (uses A0/B0)
// EPI 2: z-batched V^T: z selects (A,B); bf16 -> V^T [B*H][128][S], off=z*64
// EPI 4: z-batched fused Q+K (N=2048): z selects (A,B), off=z*64.
//        n<1024 -> Q [B,H,S,128] scaled by SL2E; n>=1024 -> K chunk-swizzled
//        (chunk' = chunk ^ (s&15)) at outp + nQKV.
template <int EPI>
__global__ void gemm128_kernel(const __bf16* __restrict__ A0, const __bf16* __restrict__ A1,
                               const __bf16* __restrict__ B0, const __bf16* __restrict__ B1,
                               int K, void* __restrict__ outp,
                               const float* __restrict__ bias) {
    const int z = blockIdx.z;
    const __bf16* __restrict__ A  = z ? A1 : A0;
    const __bf16* __restrict__ Bt = z ? B1 : B0;
    const int qkv_off = z * 64;

    __shared__ __bf16 As[128][32];
    __shared__ __bf16 Bs[128][32];
    const int t = threadIdx.x;
    const int wave = t >> 6, lane = t & 63;
    const int l15 = lane & 15, quad = lane >> 4;
    const int wm = (wave & 1) * 64, wn = (wave >> 1) * 64;
    const int m0 = blockIdx.x * 128, n0 = blockIdx.y * 128;
    const int lrow = lane >> 2;          // 0..15
    const int lcol = (lane & 3) * 8;     // 0,8,16,24

    f32x4 acc[4][4] = {};

    for (int k0 = 0; k0 < K; k0 += 32) {
        #pragma unroll
        for (int c2 = 0; c2 < 2; ++c2) {
            int rb = (wave * 2 + c2) * 16;
            GLOAD_LDS16(A  + (size_t)(m0 + rb + lrow) * K + k0 + lcol, &As[rb][0]);
            GLOAD_LDS16(Bt + (size_t)(n0 + rb + lrow) * K + k0 + lcol, &Bs[rb][0]);
        }
        __syncthreads();
        bf16x8 af[4], bfv[4];
        #pragma unroll
        for (int i = 0; i < 4; ++i) af[i]  = *(const bf16x8*)&As[wm + i * 16 + l15][quad * 8];
        #pragma unroll
        for (int i = 0; i < 4; ++i) bfv[i] = *(const bf16x8*)&Bs[wn + i * 16 + l15][quad * 8];
        #pragma unroll
        for (int mi = 0; mi < 4; ++mi)
            #pragma unroll
            for (int ni = 0; ni < 4; ++ni)
                acc[mi][ni] = __builtin_amdgcn_mfma_f32_16x16x32_bf16(af[mi], bfv[ni], acc[mi][ni], 0, 0, 0);
        __syncthreads();
    }

    const size_t nQKV = (size_t)BB * HH * SS * DHH;
    #pragma unroll
    for (int mi = 0; mi < 4; ++mi) {
        #pragma unroll
        for (int ni = 0; ni < 4; ++ni) {
            #pragma unroll
            for (int rr = 0; rr < 4; ++rr) {
                int m = m0 + wm + mi * 16 + quad * 4 + rr;
                int n = n0 + wn + ni * 16 + l15;
                if (EPI == 1) {
                    float* o = (float*)outp;
                    o[(size_t)m * 1024 + n] = acc[mi][ni][rr] + bias[n];
                } else if (EPI == 2) {
                    int h = m >> 6, dl = m & 63;
                    int b = n >> 11, s = n & (SS - 1);
                    __bf16* vt = (__bf16*)outp;
                    vt[(((size_t)b * HH + h) * DHH + dl + qkv_off) * SS + s] = (__bf16)acc[mi][ni][rr];
                } else {  // EPI 4
                    int b = m >> 11, s = m & (SS - 1);
                    int n1 = n & 1023;
                    int h = n1 >> 6, d = (n1 & 63) + qkv_off;
                    if (n < 1024) {
                        __bf16* q = (__bf16*)outp;
                        q[(((size_t)b * HH + h) * SS + s) * DHH + d] = (__bf16)(acc[mi][ni][rr] * SL2E);
                    } else {
                        int dsw = (((d >> 3) ^ (s & 15)) << 3) | (d & 7);
                        __bf16* kq = (__bf16*)outp + nQKV;
                        kq[(((size_t)b * HH + h) * SS + s) * DHH + dsw] = (__bf16)acc[mi][ni][rr];
                    }
                }
            }
        }
    }
}

// ---------------------------------------------------------------------------
// Flash attention, transposed: S^T = K Q^T (C-layout rows = kv), then P stays
// in registers as the B-operand of 16x16x16 MFMAs: O^T = V^T P^T. No P LDS
// round-trip, no mid-iteration barriers (2 barriers/kt total).
// Q: [bh][S][128] pre-scaled by SL2E; Kg: [bh][S][128] chunk-swizzled
// (chunk^(s&15)); Vg: [bh][128][S] (V^T); O: [B][S][H*128] bf16.
// 4 waves; Q tile 128 (32 m/wave = 2 mb column-blocks of S^T); KV tile 64.
// LDS 32 KB: Ks[64 kv][256B] @0; Vt[128 d][128B] @16384; epilogue reuses all
// 32 KB as O-transpose buffer [128 m][256B].
#define LDS_VT 16384
__global__ __launch_bounds__(256, 3)
void attn_kernel(const __bf16* __restrict__ Q, const __bf16* __restrict__ Kg,
                 const __bf16* __restrict__ Vg, __bf16* __restrict__ O) {
    __shared__ __align__(16) char smem[32768];

    const int t = threadIdx.x;
    const int wave = t >> 6, lane = t & 63;
    const int l15 = lane & 15, quad = lane >> 4;
    const int bh = blockIdx.y;
    const int b = bh >> 4, h = bh & 15;
    const int mt = blockIdx.x;                    // 0..15, 128-row Q tile
    const size_t base  = (size_t)bh * SS * DHH;
    const size_t vbase = (size_t)bh * DHH * SS;

    // K A-frag: row kv = nl*16+l15 (+4096*nl at use), chunk (4kst+quad)^l15
    int kaddr[4];
    #pragma unroll
    for (int kst = 0; kst < 4; ++kst)
        kaddr[kst] = l15 * 256 + (((4 * kst + quad) ^ l15) & 15) * 16;
    // V^T A-frag (b64): row d = ds*16+l15 (+2048*ds at use),
    // kv_local = nl*16 + quad*4 + j -> chunk (nl*2+(quad>>1))^(l15&7), byte (quad&1)*8
    int vaddr[4];
    #pragma unroll
    for (int nl = 0; nl < 4; ++nl)
        vaddr[nl] = LDS_VT + l15 * 128 +
                    (((nl * 2 + (quad >> 1)) ^ (l15 & 7)) & 7) * 16 + (quad & 1) * 8;

    // staging source pointers (mt-independent)
    const __bf16* kstage = Kg + base + (size_t)wave * 2048 + lane * 8;
    const __bf16* vstage = Vg + vbase + (size_t)(wave * 32 + (lane >> 3)) * SS
                           + ((lane & 7) ^ ((lane >> 3) & 7)) * 8;

    // Q B-frags (same per-lane data as A-layout), rows mt*128 + wave*32 + mb*16 + l15
    bf16x8 qf[2][4];
    #pragma unroll
    for (int mb = 0; mb < 2; ++mb) {
        int row = mt * 128 + wave * 32 + mb * 16 + l15;
        #pragma unroll
        for (int kst = 0; kst < 4; ++kst)
            qf[mb][kst] = *(const bf16x8*)(Q + base + (size_t)row * DHH + kst * 32 + quad * 8);
    }

    f32x4 oacc[2][8] = {};     // O^T: [mb][ds], row d = ds*16+quad*4+rr, col m = l15
    float li_[2] = {};         // per-lane row-sums (m = l15 fixed per lane)

    for (int kt = 0; kt < SS / 64; ++kt) {
        #pragma unroll
        for (int i = 0; i < 4; ++i)
            GLOAD_LDS16(kstage + (size_t)kt * 8192 + i * 512,
                        smem + wave * 4096 + i * 1024);
        #pragma unroll
        for (int i = 0; i < 4; ++i)
            GLOAD_LDS16(vstage + kt * 64 + (size_t)i * 8 * SS,
                        smem + LDS_VT + wave * 4096 + i * 1024);
        __syncthreads();

        // ---- S^T = K Q^T : rows kv (nl blocks), cols m (mb blocks) ----
        f32x4 sx[2][4] = {};
        #pragma unroll
        for (int kst = 0; kst < 4; ++kst) {
            #pragma unroll
            for (int nl = 0; nl < 4; ++nl) {
                bf16x8 kf = *(const bf16x8*)(smem + kaddr[kst] + 4096 * nl);
                sx[0][nl] = __builtin_amdgcn_mfma_f32_16x16x32_bf16(kf, qf[0][kst], sx[0][nl], 0, 0, 0);
                sx[1][nl] = __builtin_amdgcn_mfma_f32_16x16x32_bf16(kf, qf[1][kst], sx[1][nl], 0, 0, 0);
            }
        }

        // ---- p = exp2(s); per-lane row-sum; pack to B-operand bf16 ----
        short4v pb[2][4];
        #pragma unroll
        for (int mb = 0; mb < 2; ++mb)
            #pragma unroll
            for (int nl = 0; nl < 4; ++nl) {
                #pragma unroll
                for (int rr = 0; rr < 4; ++rr) {
                    float p = EXP2(sx[mb][nl][rr]);
                    li_[mb] += p;
                    sx[mb][nl][rr] = p;
                }
                pb[mb][nl] = pack4(sx[mb][nl]);
            }

        // ---- O^T += V^T P^T  (16x16x16, k = 16-kv block nl) ----
        #pragma unroll
        for (int nl = 0; nl < 4; ++nl) {
            #pragma unroll
            for (int ds = 0; ds < 8; ++ds) {
                short4v vf = *(const short4v*)(smem + vaddr[nl] + 2048 * ds);
                oacc[0][ds] = mfma16(vf, pb[0][nl], oacc[0][ds]);
                oacc[1][ds] = mfma16(vf, pb[1][nl], oacc[1][ds]);
            }
        }
        __syncthreads();   // all Ks/Vt reads done before next DMA overwrites
    }

    // ---- finalize row-sums (reduce across quads; m = l15 within mb) ----
    float inv[2];
    #pragma unroll
    for (int mb = 0; mb < 2; ++mb) {
        float v = li_[mb];
        v += __shfl_xor(v, 16);
        v += __shfl_xor(v, 32);
        inv[mb] = 1.f / v;
    }

    // ---- epilogue: O^T -> LDS [128 m][256B row], swizzled; then coalesced out ----
    #pragma unroll
    for (int mb = 0; mb < 2; ++mb) {
        int mloc = wave * 32 + mb * 16 + l15;
        #pragma unroll
        for (int ds = 0; ds < 8; ++ds)
            #pragma unroll
            for (int rr = 0; rr < 4; ++rr) {
                int d = ds * 16 + quad * 4 + rr;
                int addr = mloc * 256 + (((d >> 3) ^ l15) & 15) * 16 + (d & 7) * 2;
                *(__bf16*)(smem + addr) = (__bf16)(oacc[mb][ds][rr] * inv[mb]);
            }
    }
    __syncthreads();
    #pragma unroll
    for (int i = 0; i < 8; ++i) {
        int idx = t + i * 256;            // 0..2047
        int mloc = idx >> 4, cc = idx & 15;
        bf16x8 vv = *(const bf16x8*)(smem + mloc * 256 + ((cc ^ (mloc & 15)) & 15) * 16);
        int s = mt * 128 + mloc;
        *(bf16x8*)(O + ((size_t)b * SS + s) * (HH * DHH) + h * DHH + cc * 8) = vv;
    }
}

// ---------------------------------------------------------------------------
extern "C" void kernel_launch(void* const* d_in, const int* in_sizes, int n_in,
                              void* d_out, int out_size, void* d_ws, size_t ws_size,
                              hipStream_t stream) {
    const float* x      = (const float*)d_in[0];
    const float* c      = (const float*)d_in[1];
    const float* Wq_x   = (const float*)d_in[2];
    const float* Wk_x   = (const float*)d_in[3];
    const float* Wv_x   = (const float*)d_in[4];
    const float* Wq_c   = (const float*)d_in[5];
    const float* Wk_c   = (const float*)d_in[6];
    const float* Wv_c   = (const float*)d_in[7];
    const float* W_proj = (const float*)d_in[8];
    const float* b_proj = (const float*)d_in[9];

    const size_t nXC  = (size_t)BB * SS * DD;
    const size_t nW   = (size_t)DD * DD;
    const size_t nWP  = (size_t)(2 * HH * 64) * DD;
    const size_t nQKV = (size_t)BB * HH * SS * DHH;

    __bf16* ws  = (__bf16*)d_ws;
    __bf16* xb  = ws;
    __bf16* cb  = xb + nXC;
    __bf16* wt0 = cb + nXC;          // [Wq_x; Wk_x; Wv_x; Wq_c; Wk_c; Wv_c]^T contiguous
    __bf16* wt2 = wt0 + 2 * nW;      // Wv_x^T
    __bf16* wt3 = wt0 + 3 * nW;      // Wq_c^T (c's Q,K pair start)
    __bf16* wt5 = wt0 + 5 * nW;      // Wv_c^T
    __bf16* wtp = wt0 + 6 * nW;      // W_proj^T [1024][2048]
    __bf16* Qb  = wtp + nWP;
    __bf16* Kb  = Qb + nQKV;         // MUST stay at Qb + nQKV (EPI4 assumes it)
    __bf16* Vb  = Kb + nQKV;         // [B*H][128][S] pre-transposed
    __bf16* Ob  = xb;                // alias x/c region (dead after QKV GEMMs)

    cast2_kernel<<<(int)(2 * nXC / 1024), 256, 0, stream>>>(x, c, xb, (int)nXC);

    transpose6_kernel<<<dim3(32, 32, 6), dim3(32, 8), 0, stream>>>(
        Wq_x, Wk_x, Wv_x, Wq_c, Wk_c, Wv_c, wt0);
    transpose_cast_kernel<<<dim3(32, 64), dim3(32, 8), 0, stream>>>(W_proj, wtp, 2048, 1024);

    // z-batched fused Q+K GEMMs (M=8192, N=2048, K=1024): z=0 x-path, z=1 c-path
    gemm128_kernel<4><<<dim3(64, 16, 2), 256, 0, stream>>>(xb, cb, wt0, wt3, 1024, Qb, nullptr);
    // z-batched V GEMMs (A = Wv^T, B = activations) -> V^T [bh][d][s]
    gemm128_kernel<2><<<dim3(8, 64, 2), 256, 0, stream>>>(wt2, wt5, xb, cb, 1024, Vb, nullptr);

    // attention (writes Ob = [B,S,H*128] bf16), Q tile 128 -> grid 16 x 64
    attn_kernel<<<dim3(16, 64), 256, 0, stream>>>(Qb, Kb, Vb, Ob);

    // projection (M=8192, K=2048, N=1024) + bias -> fp32 out
    gemm128_kernel<1><<<dim3(64, 8, 1), 256, 0, stream>>>(Ob, nullptr, wtp, nullptr, 2048, d_out, b_proj);
}

// Round 9
// 488.520 us; speedup vs baseline: 1.0127x; 1.0127x over previous
//
#include <hip/hip_runtime.h>
#include <hip/hip_bf16.h>
#include <stdint.h>

// Problem constants
#define BB 4
#define SS 2048
#define DD 1024
#define HH 16
#define DHH 128   // per-head dim after concat (2*64)

typedef __bf16 bf16x8 __attribute__((ext_vector_type(8)));
typedef __bf16 bf16x4 __attribute__((ext_vector_type(4)));
typedef float  f32x4  __attribute__((ext_vector_type(4)));
typedef short  short4v __attribute__((ext_vector_type(4)));

// (1/sqrt(64)) * log2(e), folded into Q at GEMM epilogue time
#define SL2E 0.180336880111186f

#if __has_builtin(__builtin_amdgcn_exp2f)
#define EXP2(x) __builtin_amdgcn_exp2f(x)
#else
#define EXP2(x) exp2f(x)
#endif

// async global->LDS, 16B per lane; LDS dest is wave-uniform base + lane*16,
// global src is per-lane (gather allowed)
#define GLOAD_LDS16(gp, lp) \
  __builtin_amdgcn_global_load_lds((const __attribute__((address_space(1))) unsigned int*)(gp), \
                                   (__attribute__((address_space(3))) unsigned int*)(lp), 16, 0, 0)

// 16x16x16 bf16 MFMA (k=16): B-operand k = quad*4+j == S^T C-layout rows.
static __device__ inline f32x4 mfma16(short4v a, short4v b, f32x4 c) {
#if __has_builtin(__builtin_amdgcn_mfma_f32_16x16x16bf16_1k)
    return __builtin_amdgcn_mfma_f32_16x16x16bf16_1k(a, b, c, 0, 0, 0);
#else
    asm volatile("v_mfma_f32_16x16x16_bf16 %0, %1, %2, %0" : "+v"(c) : "v"(a), "v"(b));
    return c;
#endif
}

static __device__ inline short4v pack4(f32x4 v) {
    bf16x4 t;
    t[0] = (__bf16)v[0]; t[1] = (__bf16)v[1]; t[2] = (__bf16)v[2]; t[3] = (__bf16)v[3];
    return __builtin_bit_cast(short4v, t);
}

// ---------------------------------------------------------------------------
// Fused cast of x and c -> bf16 (dest xb and cb are contiguous)
__global__ void cast2_kernel(const float* __restrict__ x, const float* __restrict__ c,
                             __bf16* __restrict__ out, int n) {
    int i = (blockIdx.x * blockDim.x + threadIdx.x) * 4;
    const float* src = (i < n) ? (x + i) : (c + (i - n));
    f32x4 v = *(const f32x4*)src;
    bf16x4 o;
    o[0] = (__bf16)v[0]; o[1] = (__bf16)v[1]; o[2] = (__bf16)v[2]; o[3] = (__bf16)v[3];
    *(bf16x4*)(out + i) = o;
}

// ---------------------------------------------------------------------------
// Fused transpose+cast of all 8 weight slices:
// z 0..5: QKV weights 1024x1024 -> wt0 + z*1M, out stride 1024
// z 6..7: W_proj k-halves      -> wtp, out stride 2048, k-offset z'*1024
__global__ void transpose8_kernel(const float* s0, const float* s1, const float* s2,
                                  const float* s3, const float* s4, const float* s5,
                                  const float* sp, __bf16* __restrict__ wt0,
                                  __bf16* __restrict__ wtp) {
    const int z = blockIdx.z;
    const float* srcs[8] = {s0, s1, s2, s3, s4, s5, sp, sp + 1024 * 1024};
    const float* __restrict__ in = srcs[z];
    __bf16* __restrict__ out = (z < 6) ? (wt0 + (size_t)z * 1024 * 1024) : wtp;
    const int ostride = (z < 6) ? 1024 : 2048;
    const int koff    = (z < 7) ? 0 : 1024;

    __shared__ float tile[32][33];
    int n0 = blockIdx.x * 32, k0 = blockIdx.y * 32;
    int tx = threadIdx.x, ty = threadIdx.y;   // 32 x 8
    #pragma unroll
    for (int i = 0; i < 32; i += 8)
        tile[ty + i][tx] = in[(size_t)(k0 + ty + i) * 1024 + n0 + tx];
    __syncthreads();
    #pragma unroll
    for (int i = 0; i < 32; i += 8)
        out[(size_t)(n0 + ty + i) * ostride + koff + k0 + tx] = (__bf16)tile[tx][ty + i];
}

// ---------------------------------------------------------------------------
// GEMM: C = A @ Bt^T (bf16, both contiguous in K), 128x128 tile, BK=32,
// global_load_lds staging, 4 waves, 4x4 16x16x32 subtiles.
// EPI 1: fp32 -> out[M][1024] + bias (direct stores; uses A0/B0)
// EPI 5: z-batched fused Q+K+V (N=3072, weights [Wq;Wk;Wv] per z), LDS-staged
//        coalesced epilogue. n<1024: Q [B,H,S,128] scaled by SL2E;
//        1024..2047: K same layout chunk-swizzled (chunk' = chunk^(s&15)) at
//        outp+nQKV; >=2048: V^T [B*H][128][S] at outp+2*nQKV. off=z*64.
template <int EPI>
__global__ void gemm128_kernel(const __bf16* __restrict__ A0, const __bf16* __restrict__ A1,
                               const __bf16* __restrict__ B0, const __bf16* __restrict__ B1,
                               int K, void* __restrict__ outp,
                               const float* __restrict__ bias) {
    const int z = blockIdx.z;
    const __bf16* __restrict__ A  = z ? A1 : A0;
    const __bf16* __restrict__ Bt = z ? B1 : B0;
    const int qkv_off = z * 64;

    __shared__ __align__(16) char gsm[16384];
    __bf16 (*As)[32] = (__bf16 (*)[32])gsm;
    __bf16 (*Bs)[32] = (__bf16 (*)[32])(gsm + 8192);

    const int t = threadIdx.x;
    const int wave = t >> 6, lane = t & 63;
    const int l15 = lane & 15, quad = lane >> 4;
    const int wm = (wave & 1) * 64, wn = (wave >> 1) * 64;
    const int m0 = blockIdx.x * 128, n0 = blockIdx.y * 128;
    const int lrow = lane >> 2;          // 0..15
    const int lcol = (lane & 3) * 8;     // 0,8,16,24

    f32x4 acc[4][4] = {};

    for (int k0 = 0; k0 < K; k0 += 32) {
        #pragma unroll
        for (int c2 = 0; c2 < 2; ++c2) {
            int rb = (wave * 2 + c2) * 16;
            GLOAD_LDS16(A  + (size_t)(m0 + rb + lrow) * K + k0 + lcol, &As[rb][0]);
            GLOAD_LDS16(Bt + (size_t)(n0 + rb + lrow) * K + k0 + lcol, &Bs[rb][0]);
        }
        __syncthreads();
        bf16x8 af[4], bfv[4];
        #pragma unroll
        for (int i = 0; i < 4; ++i) af[i]  = *(const bf16x8*)&As[wm + i * 16 + l15][quad * 8];
        #pragma unroll
        for (int i = 0; i < 4; ++i) bfv[i] = *(const bf16x8*)&Bs[wn + i * 16 + l15][quad * 8];
        #pragma unroll
        for (int mi = 0; mi < 4; ++mi)
            #pragma unroll
            for (int ni = 0; ni < 4; ++ni)
                acc[mi][ni] = __builtin_amdgcn_mfma_f32_16x16x32_bf16(af[mi], bfv[ni], acc[mi][ni], 0, 0, 0);
        __syncthreads();   // also guarantees LDS is dead before epilogue reuse
    }

    const size_t nQKV = (size_t)BB * HH * SS * DHH;

    if (EPI == 1) {
        #pragma unroll
        for (int mi = 0; mi < 4; ++mi)
            #pragma unroll
            for (int ni = 0; ni < 4; ++ni)
                #pragma unroll
                for (int rr = 0; rr < 4; ++rr) {
                    int m = m0 + wm + mi * 16 + quad * 4 + rr;
                    int n = n0 + wn + ni * 16 + l15;
                    float* o = (float*)outp;
                    o[(size_t)m * 1024 + n] = acc[mi][ni][rr] + bias[n];
                }
        return;
    }

    // ---- EPI 5: LDS-staged coalesced epilogue (wave-private 4 KB region) ----
    char* reg = gsm + wave * 4096;
    const int path = (n0 + wn) >> 10;     // wave-uniform: 0=Q, 1=K, 2=V

    #pragma unroll
    for (int np = 0; np < 2; ++np) {      // two 32-wide n strips per wave
        // stage acc strip into LDS
        if (path < 2) {
            // [64 m][32 n] row-major, 2-way max conflicts
            #pragma unroll
            for (int mi = 0; mi < 4; ++mi)
                #pragma unroll
                for (int nn = 0; nn < 2; ++nn) {
                    int ni = np * 2 + nn;
                    #pragma unroll
                    for (int rr = 0; rr < 4; ++rr) {
                        int ml = mi * 16 + quad * 4 + rr, nl = nn * 16 + l15;
                        float v = acc[mi][ni][rr];
                        if (path == 0) v *= SL2E;
                        *(__bf16*)(reg + ml * 64 + nl * 2) = (__bf16)v;
                    }
                }
        } else {
            // transposed [32 n][64 m], chunk swizzled: c ^= (ml>>3)
            #pragma unroll
            for (int mi = 0; mi < 4; ++mi)
                #pragma unroll
                for (int nn = 0; nn < 2; ++nn) {
                    int ni = np * 2 + nn;
                    #pragma unroll
                    for (int rr = 0; rr < 4; ++rr) {
                        int ml = mi * 16 + quad * 4 + rr, nl = nn * 16 + l15;
                        int ad = nl * 128 + ((((ml >> 3) ^ (nl & 7)) & 7) * 16) + (ml & 7) * 2;
                        *(__bf16*)(reg + ad) = (__bf16)acc[mi][ni][rr];
                    }
                }
        }
        // coalesced b128 stores (wave-private LDS; compiler inserts lgkm waits)
        int nbase = n0 + wn + np * 32;
        if (path == 0) {
            __bf16* q = (__bf16*)outp;
            #pragma unroll
            for (int i = 0; i < 4; ++i) {
                int ml = i * 16 + (lane >> 2), ng = (lane & 3) * 8;
                bf16x8 v = *(const bf16x8*)(reg + ml * 64 + ng * 2);
                int m = m0 + wm + ml;
                int b = m >> 11, s = m & (SS - 1);
                int n1 = (nbase + ng) & 1023;
                int h = n1 >> 6, d = (n1 & 63) + qkv_off;
                *(bf16x8*)(q + (((size_t)b * HH + h) * SS + s) * DHH + d) = v;
            }
        } else if (path == 1) {
            __bf16* kq = (__bf16*)outp + nQKV;
            #pragma unroll
            for (int i = 0; i < 4; ++i) {
                int ml = i * 16 + (lane >> 2), ng = (lane & 3) * 8;
                bf16x8 v = *(const bf16x8*)(reg + ml * 64 + ng * 2);
                int m = m0 + wm + ml;
                int b = m >> 11, s = m & (SS - 1);
                int n1 = (nbase + ng) & 1023;
                int h = n1 >> 6, d = (n1 & 63) + qkv_off;
                int dsw = (((d >> 3) ^ (s & 15)) << 3);   // d&7 == 0 at group base
                *(bf16x8*)(kq + (((size_t)b * HH + h) * SS + s) * DHH + dsw) = v;
            }
        } else {
            __bf16* vt = (__bf16*)outp + 2 * nQKV;
            #pragma unroll
            for (int i = 0; i < 4; ++i) {
                int dl = i * 8 + (lane >> 3), sg = (lane & 7) * 8;
                int chunk = ((lane & 7) ^ (dl & 7)) & 7;
                bf16x8 v = *(const bf16x8*)(reg + dl * 128 + chunk * 16);
                int n2 = (nbase + dl) & 1023;
                int h = n2 >> 6, d = (n2 & 63) + qkv_off;
                int m = m0 + wm + sg;
                int b = m >> 11, s = m & (SS - 1);
                *(bf16x8*)(vt + (((size_t)b * HH + h) * DHH + d) * SS + s) = v;
            }
        }
    }
}

// ---------------------------------------------------------------------------
// Flash attention (unchanged from R8), transposed: S^T = K Q^T, P stays in
// registers as B-operand of 16x16x16 MFMAs: O^T = V^T P^T.
// Q: [bh][S][128] pre-scaled by SL2E; Kg: [bh][S][128] chunk-swizzled
// (chunk^(s&15)); Vg: [bh][128][S] (V^T); O: [B][S][H*128] bf16.
#define LDS_VT 16384
__global__ __launch_bounds__(256, 3)
void attn_kernel(const __bf16* __restrict__ Q, const __bf16* __restrict__ Kg,
                 const __bf16* __restrict__ Vg, __bf16* __restrict__ O) {
    __shared__ __align__(16) char smem[32768];

    const int t = threadIdx.x;
    const int wave = t >> 6, lane = t & 63;
    const int l15 = lane & 15, quad = lane >> 4;
    const int bh = blockIdx.y;
    const int b = bh >> 4, h = bh & 15;
    const int mt = blockIdx.x;                    // 0..15, 128-row Q tile
    const size_t base  = (size_t)bh * SS * DHH;
    const size_t vbase = (size_t)bh * DHH * SS;

    int kaddr[4];
    #pragma unroll
    for (int kst = 0; kst < 4; ++kst)
        kaddr[kst] = l15 * 256 + (((4 * kst + quad) ^ l15) & 15) * 16;
    int vaddr[4];
    #pragma unroll
    for (int nl = 0; nl < 4; ++nl)
        vaddr[nl] = LDS_VT + l15 * 128 +
                    (((nl * 2 + (quad >> 1)) ^ (l15 & 7)) & 7) * 16 + (quad & 1) * 8;

    const __bf16* kstage = Kg + base + (size_t)wave * 2048 + lane * 8;
    const __bf16* vstage = Vg + vbase + (size_t)(wave * 32 + (lane >> 3)) * SS
                           + ((lane & 7) ^ ((lane >> 3) & 7)) * 8;

    bf16x8 qf[2][4];
    #pragma unroll
    for (int mb = 0; mb < 2; ++mb) {
        int row = mt * 128 + wave * 32 + mb * 16 + l15;
        #pragma unroll
        for (int kst = 0; kst < 4; ++kst)
            qf[mb][kst] = *(const bf16x8*)(Q + base + (size_t)row * DHH + kst * 32 + quad * 8);
    }

    f32x4 oacc[2][8] = {};
    float li_[2] = {};

    for (int kt = 0; kt < SS / 64; ++kt) {
        #pragma unroll
        for (int i = 0; i < 4; ++i)
            GLOAD_LDS16(kstage + (size_t)kt * 8192 + i * 512,
                        smem + wave * 4096 + i * 1024);
        #pragma unroll
        for (int i = 0; i < 4; ++i)
            GLOAD_LDS16(vstage + kt * 64 + (size_t)i * 8 * SS,
                        smem + LDS_VT + wave * 4096 + i * 1024);
        __syncthreads();

        f32x4 sx[2][4] = {};
        #pragma unroll
        for (int kst = 0; kst < 4; ++kst) {
            #pragma unroll
            for (int nl = 0; nl < 4; ++nl) {
                bf16x8 kf = *(const bf16x8*)(smem + kaddr[kst] + 4096 * nl);
                sx[0][nl] = __builtin_amdgcn_mfma_f32_16x16x32_bf16(kf, qf[0][kst], sx[0][nl], 0, 0, 0);
                sx[1][nl] = __builtin_amdgcn_mfma_f32_16x16x32_bf16(kf, qf[1][kst], sx[1][nl], 0, 0, 0);
            }
        }

        short4v pb[2][4];
        #pragma unroll
        for (int mb = 0; mb < 2; ++mb)
            #pragma unroll
            for (int nl = 0; nl < 4; ++nl) {
                #pragma unroll
                for (int rr = 0; rr < 4; ++rr) {
                    float p = EXP2(sx[mb][nl][rr]);
                    li_[mb] += p;
                    sx[mb][nl][rr] = p;
                }
                pb[mb][nl] = pack4(sx[mb][nl]);
            }

        #pragma unroll
        for (int nl = 0; nl < 4; ++nl) {
            #pragma unroll
            for (int ds = 0; ds < 8; ++ds) {
                short4v vf = *(const short4v*)(smem + vaddr[nl] + 2048 * ds);
                oacc[0][ds] = mfma16(vf, pb[0][nl], oacc[0][ds]);
                oacc[1][ds] = mfma16(vf, pb[1][nl], oacc[1][ds]);
            }
        }
        __syncthreads();
    }

    float inv[2];
    #pragma unroll
    for (int mb = 0; mb < 2; ++mb) {
        float v = li_[mb];
        v += __shfl_xor(v, 16);
        v += __shfl_xor(v, 32);
        inv[mb] = 1.f / v;
    }

    #pragma unroll
    for (int mb = 0; mb < 2; ++mb) {
        int mloc = wave * 32 + mb * 16 + l15;
        #pragma unroll
        for (int ds = 0; ds < 8; ++ds)
            #pragma unroll
            for (int rr = 0; rr < 4; ++rr) {
                int d = ds * 16 + quad * 4 + rr;
                int addr = mloc * 256 + (((d >> 3) ^ l15) & 15) * 16 + (d & 7) * 2;
                *(__bf16*)(smem + addr) = (__bf16)(oacc[mb][ds][rr] * inv[mb]);
            }
    }
    __syncthreads();
    #pragma unroll
    for (int i = 0; i < 8; ++i) {
        int idx = t + i * 256;
        int mloc = idx >> 4, cc = idx & 15;
        bf16x8 vv = *(const bf16x8*)(smem + mloc * 256 + ((cc ^ (mloc & 15)) & 15) * 16);
        int s = mt * 128 + mloc;
        *(bf16x8*)(O + ((size_t)b * SS + s) * (HH * DHH) + h * DHH + cc * 8) = vv;
    }
}

// ---------------------------------------------------------------------------
extern "C" void kernel_launch(void* const* d_in, const int* in_sizes, int n_in,
                              void* d_out, int out_size, void* d_ws, size_t ws_size,
                              hipStream_t stream) {
    const float* x      = (const float*)d_in[0];
    const float* c      = (const float*)d_in[1];
    const float* Wq_x   = (const float*)d_in[2];
    const float* Wk_x   = (const float*)d_in[3];
    const float* Wv_x   = (const float*)d_in[4];
    const float* Wq_c   = (const float*)d_in[5];
    const float* Wk_c   = (const float*)d_in[6];
    const float* Wv_c   = (const float*)d_in[7];
    const float* W_proj = (const float*)d_in[8];
    const float* b_proj = (const float*)d_in[9];

    const size_t nXC  = (size_t)BB * SS * DD;
    const size_t nW   = (size_t)DD * DD;
    const size_t nWP  = (size_t)(2 * HH * 64) * DD;
    const size_t nQKV = (size_t)BB * HH * SS * DHH;

    __bf16* ws  = (__bf16*)d_ws;
    __bf16* xb  = ws;
    __bf16* cb  = xb + nXC;
    __bf16* wt0 = cb + nXC;          // [Wq_x; Wk_x; Wv_x; Wq_c; Wk_c; Wv_c]^T contiguous
    __bf16* wt3 = wt0 + 3 * nW;      // c's weight triple
    __bf16* wtp = wt0 + 6 * nW;      // W_proj^T [1024][2048]
    __bf16* Qb  = wtp + nWP;
    __bf16* Kb  = Qb + nQKV;         // MUST stay at Qb + nQKV (EPI5 assumes it)
    __bf16* Vb  = Kb + nQKV;         // MUST stay at Qb + 2*nQKV (EPI5 assumes it)
    __bf16* Ob  = xb;                // alias x/c region (dead after QKV GEMM)

    cast2_kernel<<<(int)(2 * nXC / 1024), 256, 0, stream>>>(x, c, xb, (int)nXC);

    transpose8_kernel<<<dim3(32, 32, 8), dim3(32, 8), 0, stream>>>(
        Wq_x, Wk_x, Wv_x, Wq_c, Wk_c, Wv_c, W_proj, wt0, wtp);

    // ONE fused Q+K+V GEMM, z-batched over {x,c}: M=8192, N=3072, K=1024
    gemm128_kernel<5><<<dim3(64, 24, 2), 256, 0, stream>>>(xb, cb, wt0, wt3, 1024, Qb, nullptr);

    // attention (writes Ob = [B,S,H*128] bf16), Q tile 128 -> grid 16 x 64
    attn_kernel<<<dim3(16, 64), 256, 0, stream>>>(Qb, Kb, Vb, Ob);

    // projection (M=8192, K=2048, N=1024) + bias -> fp32 out
    gemm128_kernel<1><<<dim3(64, 8, 1), 256, 0, stream>>>(Ob, nullptr, wtp, nullptr, 2048, d_out, b_proj);
}